// Round 13
// baseline (438.515 us; speedup 1.0000x reference)
//
#include <hip/hip_runtime.h>
#include <stdint.h>
#include <stddef.h>

#define Bsz 16384
#define Hsz 512
#define KG 1536   // K of gemm2 == row stride of A
#define KA 1024   // K of gemm1
#define NT2 24    // gemm2 K tiles of 64

typedef float f32x4 __attribute__((ext_vector_type(4)));
typedef short bf16x8 __attribute__((ext_vector_type(8)));
typedef unsigned short u16;
typedef unsigned int u32;

__device__ __forceinline__ u16 f2bf(float f) {
  union { float f; unsigned u; } v; v.f = f;
  return (u16)((v.u + 0x7fffu + ((v.u >> 16) & 1u)) >> 16);
}
__device__ __forceinline__ float bf2f(u16 h) {
  union { unsigned u; float f; } v; v.u = ((unsigned)h) << 16;
  return v.f;
}
__device__ __forceinline__ float sigm(float x) {
  return 1.0f / (1.0f + __expf(-x));
}
__device__ __forceinline__ float tanh_(float x) {
  x = fminf(fmaxf(x, -15.0f), 15.0f);
  float e = __expf(2.0f * x);
  return (e - 1.0f) / (e + 1.0f);
}

__device__ __forceinline__ void gload_lds16(const u16* g, u16* l) {
  __builtin_amdgcn_global_load_lds(
      (__attribute__((address_space(1))) void*)(g),
      (__attribute__((address_space(3))) void*)(l), 16, 0, 0);
}

#define VMCNT(n) asm volatile("s_waitcnt vmcnt(" #n ")" ::: "memory")
#define LGKM0() { asm volatile("s_waitcnt lgkmcnt(0)" ::: "memory"); \
                  __builtin_amdgcn_sched_barrier(0); }
#define BAR() { asm volatile("" ::: "memory"); __builtin_amdgcn_s_barrier(); \
                asm volatile("" ::: "memory"); }
#define DSR(dst, addr, OFF) \
  asm volatile("ds_read_b128 %0, %1 offset:" #OFF : "=v"(dst) : "v"(addr));

// ---- cast h_prev | x_t into bf16 A[B][1536] (cols 0..1023) ----
__global__ __launch_bounds__(256) void prep_A_kernel(
    const float* __restrict__ h_prev, const float* __restrict__ x_t,
    u16* __restrict__ A) {
  const int b = blockIdx.x;
  const int q = threadIdx.x;
  const int qq = q & 127;
  const float4* src = (q < 128) ? (const float4*)h_prev : (const float4*)x_t;
  float4 v = src[(size_t)b * 128 + qq];
  ushort4 o;
  o.x = f2bf(v.x); o.y = f2bf(v.y); o.z = f2bf(v.z); o.w = f2bf(v.w);
  *(ushort4*)(A + (size_t)b * KG + (size_t)q * 4) = o;
}

// ---- transpose-cast: in[R][C] fp32 -> out[C][R] bf16 ----
__global__ __launch_bounds__(256) void transpose_cast_kernel(
    const float* __restrict__ in, u16* __restrict__ out, int R, int C) {
  __shared__ float tile[32][33];
  const int c0 = blockIdx.x * 32;
  const int r0 = blockIdx.y * 32;
  const int tx = threadIdx.x;
  const int ty = threadIdx.y;
  #pragma unroll
  for (int i = ty; i < 32; i += 8)
    tile[i][tx] = in[(size_t)(r0 + i) * C + (c0 + tx)];
  __syncthreads();
  #pragma unroll
  for (int i = ty; i < 32; i += 8)
    out[(size_t)(c0 + i) * R + (r0 + tx)] = f2bf(tile[tx][i]);
}

// ---- GEMM1: s = tanh(A[:,0:1024] @ Wst^T + delta*ws_last + bs) -> A[:,1024:1536]
__global__ __launch_bounds__(256, 2) void gemm1_kernel(
    const u16* __restrict__ A, const u16* __restrict__ Wst,
    const float* __restrict__ Ws, const float* __restrict__ bs,
    const float* __restrict__ delta, u16* __restrict__ Aout) {
  __shared__ __attribute__((aligned(16))) u16 Als[128][32];
  __shared__ __attribute__((aligned(16))) u16 Bls[128][32];
  const int t = threadIdx.x;
  const int w = t >> 6, l = t & 63;
  const int bm0 = blockIdx.y * 128;
  const int bn0 = blockIdx.x * 128;
  const int wm = w >> 1, wn = w & 1;

  f32x4 zv = {0.f, 0.f, 0.f, 0.f};
  f32x4 acc[4][4];
  #pragma unroll
  for (int i = 0; i < 4; ++i)
    #pragma unroll
    for (int j = 0; j < 4; ++j) acc[i][j] = zv;

  const int r = t >> 2, q = t & 3;
  const u16* gA0 = A + (size_t)(bm0 + r) * KG + q * 8;
  const u16* gA1 = A + (size_t)(bm0 + 64 + r) * KG + q * 8;
  const u16* gB0 = Wst + (size_t)(bn0 + r) * KA + q * 8;
  const u16* gB1 = Wst + (size_t)(bn0 + 64 + r) * KA + q * 8;
  u16* lA0 = &Als[0][0] + w * 512;
  u16* lA1 = &Als[0][0] + 2048 + w * 512;
  u16* lB0 = &Bls[0][0] + w * 512;
  u16* lB1 = &Bls[0][0] + 2048 + w * 512;

  const int frow = l & 15;
  const int kofs = (l >> 4) * 8;

  for (int kt = 0; kt < KA / 32; ++kt) {
    const int ko = kt * 32;
    gload_lds16(gA0 + ko, lA0);
    gload_lds16(gA1 + ko, lA1);
    gload_lds16(gB0 + ko, lB0);
    gload_lds16(gB1 + ko, lB1);
    __syncthreads();
    bf16x8 af[4], bfv[4];
    #pragma unroll
    for (int mi = 0; mi < 4; ++mi)
      af[mi] = *(const bf16x8*)&Als[wm * 64 + mi * 16 + frow][kofs];
    #pragma unroll
    for (int ni = 0; ni < 4; ++ni)
      bfv[ni] = *(const bf16x8*)&Bls[wn * 64 + ni * 16 + frow][kofs];
    #pragma unroll
    for (int mi = 0; mi < 4; ++mi)
      #pragma unroll
      for (int ni = 0; ni < 4; ++ni)
        acc[mi][ni] = __builtin_amdgcn_mfma_f32_16x16x32_bf16(
            af[mi], bfv[ni], acc[mi][ni], 0, 0, 0);
    __syncthreads();
  }

  #pragma unroll
  for (int ni = 0; ni < 4; ++ni) {
    const int col = bn0 + wn * 64 + ni * 16 + (l & 15);
    const float wsl = Ws[(size_t)1024 * 512 + col];
    const float bsv = bs[col];
    #pragma unroll
    for (int mi = 0; mi < 4; ++mi) {
      #pragma unroll
      for (int rr = 0; rr < 4; ++rr) {
        const int row = bm0 + wm * 64 + mi * 16 + (l >> 4) * 4 + rr;
        const float z = acc[mi][ni][rr] + delta[row] * wsl + bsv;
        Aout[(size_t)row * KG + 1024 + col] = f2bf(tanh_(z));
      }
    }
  }
}

// ---- GEMM2 fused, template cadence: 256 x (5x64) tile, BK=64, 4 phases ----
// Grid 512 = 64 rb x 8 hb (hb = XCD pin; exactly 2 dispatch rounds).
// 8 waves 2Mx4N; wave C = 128 x (5x16); acc[8][5] (AGPR file).
// LDS: LA[2][256x64] 64KB + LB[2][320x64] 80KB = 144KB, 1 block/CU.
// Per group (tile t, buf NB=t&1): 4 phases (ks,mh); all 9 stage-gloads
// for tile t+1 (buf 1-NB) issued in phases 1-2 -> group-end VMCNT(0)
// targets loads with >=2-phase (~1500cyc) lead = free drain.
// Phase: ds_reads (asm) -> stages -> BAR -> LGKM0 -> setprio 20 MFMA -> BAR.
// Swizzle (gemm2_t-verified, 0 conflicts): 128B rows, LDS chunk c stores
// global chunk c^(row&7) via pre-swizzled src; read chunk (ks*4+kq)^(frow&7)
// (ks-flip = addr XOR 64 -> K1 addr regs).
__global__ __launch_bounds__(512, 2) void gemm2_f(
    const u16* __restrict__ A, const u16* __restrict__ Wgt,
    const float* __restrict__ bg, const float* __restrict__ c_prev,
    float* __restrict__ out) {
  __shared__ __attribute__((aligned(16))) u16 LA[2][256 * 64];
  __shared__ __attribute__((aligned(16))) u16 LB[2][320 * 64];

  const int t5 = threadIdx.x;
  const int w = t5 >> 6, l = t5 & 63;
  const int bid = blockIdx.x;
  const int hb = bid & 7;
  const int rb = bid >> 3;
  const int bm0 = rb * 256;
  const int h0 = hb * 64;
  const int wm = w >> 2;        // M half (128 rows)
  const int wn = w & 3;         // 16-col group within each gate's 64

  // ---- staging sources (pre-swizzled global chunks, linear LDS dest) ----
  const u16* Asrc[4];
  const u16* Bsrc[5];
  #pragma unroll
  for (int j = 0; j < 4; ++j) {
    u32 d = (u32)(t5 + j * 512) * 16;
    u32 row = d >> 7;
    u32 ch = ((d >> 4) & 7) ^ (row & 7);
    Asrc[j] = A + (size_t)(bm0 + row) * KG + ch * 8;
  }
  #pragma unroll
  for (int j = 0; j < 5; ++j) {
    u32 d = (u32)(t5 + j * 512) * 16;
    u32 brow = d >> 7;                    // 0..319
    u32 g = brow >> 6, hl = brow & 63;
    u32 ch = ((d >> 4) & 7) ^ (brow & 7);
    Bsrc[j] = Wgt + (size_t)(g * Hsz + h0 + hl) * KG + ch * 8;
  }

#define STG_A(j, NB, tl) gload_lds16(Asrc[j] + (size_t)(tl) * 64, \
    &LA[NB][0] + t5 * 8 + (j) * 4096);
#define STG_B(j, NB, tl) gload_lds16(Bsrc[j] + (size_t)(tl) * 64, \
    &LB[NB][0] + t5 * 8 + (j) * 4096);

  // ---- accumulators (AGPR) ----
  f32x4 acc[8][5];
  f32x4 zv = {0.f, 0.f, 0.f, 0.f};
  #pragma unroll
  for (int mi = 0; mi < 8; ++mi)
    #pragma unroll
    for (int g = 0; g < 5; ++g) acc[mi][g] = zv;

  // ---- fragment read addresses (bytes) ----
  const int frow = l & 15, kq = l >> 4;
  const u32 chunk0 = (u32)(((kq ^ (frow & 3)) * 16) + ((frow & 4) * 16));
  const u32 ldsAb = (u32)(uintptr_t)&LA[0][0];
  const u32 ldsBb = (u32)(uintptr_t)&LB[0][0];
  const u32 aK0b0 = ldsAb + (u32)wm * 16384 + (u32)frow * 128 + chunk0;
  const u32 aK1b0 = aK0b0 ^ 64;
  const u32 aK0b1 = aK0b0 + 32768;
  const u32 aK1b1 = aK1b0 + 32768;
  const u32 bK0b0 = ldsBb + (u32)(wn * 16 + frow) * 128 + chunk0;
  const u32 bK1b0 = bK0b0 ^ 64;
  const u32 bK0b1 = bK0b0 + 40960;
  const u32 bK1b1 = bK1b0 + 40960;

  bf16x8 af0, af1, af2, af3, bf0, bf1, bf2, bf3, bf4;

#define RD_A(AK, MHOFF0, MHOFF1, MHOFF2, MHOFF3) { \
    DSR(af0, AK, MHOFF0) DSR(af1, AK, MHOFF1) \
    DSR(af2, AK, MHOFF2) DSR(af3, AK, MHOFF3) }
#define RD_B(BK) { DSR(bf0, BK, 0) DSR(bf1, BK, 8192) DSR(bf2, BK, 16384) \
    DSR(bf3, BK, 24576) DSR(bf4, BK, 32768) }
#define MFMA20(MH) { __builtin_amdgcn_s_setprio(1); \
    _Pragma("unroll") \
    for (int g = 0; g < 5; ++g) { \
      bf16x8 bb = (g == 0) ? bf0 : (g == 1) ? bf1 : (g == 2) ? bf2 \
                  : (g == 3) ? bf3 : bf4; \
      acc[(MH) * 4 + 0][g] = __builtin_amdgcn_mfma_f32_16x16x32_bf16(af0, bb, acc[(MH) * 4 + 0][g], 0, 0, 0); \
      acc[(MH) * 4 + 1][g] = __builtin_amdgcn_mfma_f32_16x16x32_bf16(af1, bb, acc[(MH) * 4 + 1][g], 0, 0, 0); \
      acc[(MH) * 4 + 2][g] = __builtin_amdgcn_mfma_f32_16x16x32_bf16(af2, bb, acc[(MH) * 4 + 2][g], 0, 0, 0); \
      acc[(MH) * 4 + 3][g] = __builtin_amdgcn_mfma_f32_16x16x32_bf16(af3, bb, acc[(MH) * 4 + 3][g], 0, 0, 0); \
    } \
    __builtin_amdgcn_s_setprio(0); }

  // GROUP: consume tile t via (AK0,AK1,BK0,BK1); stage tile t+1 into NB2.
#define GROUP(AK0, AK1, BK0, BK1, NB2, tl, st) { \
    /* ph1: ks0, mh0 */ \
    RD_A(AK0, 0, 2048, 4096, 6144) \
    RD_B(BK0) \
    if (st) { STG_A(0, NB2, tl) STG_A(1, NB2, tl) STG_B(0, NB2, tl) STG_B(1, NB2, tl) } \
    BAR(); LGKM0(); MFMA20(0) BAR(); \
    /* ph2: ks0, mh1 */ \
    RD_A(AK0, 8192, 10240, 12288, 14336) \
    if (st) { STG_A(2, NB2, tl) STG_A(3, NB2, tl) STG_B(2, NB2, tl) STG_B(3, NB2, tl) STG_B(4, NB2, tl) } \
    BAR(); LGKM0(); MFMA20(1) BAR(); \
    /* ph3: ks1, mh0 */ \
    RD_A(AK1, 0, 2048, 4096, 6144) \
    RD_B(BK1) \
    BAR(); LGKM0(); MFMA20(0) BAR(); \
    /* ph4: ks1, mh1 */ \
    RD_A(AK1, 8192, 10240, 12288, 14336) \
    BAR(); LGKM0(); MFMA20(1) \
    VMCNT(0); BAR(); }

  // prologue: stage tile 0 into buf 0
  STG_A(0, 0, 0) STG_A(1, 0, 0) STG_A(2, 0, 0) STG_A(3, 0, 0)
  STG_B(0, 0, 0) STG_B(1, 0, 0) STG_B(2, 0, 0) STG_B(3, 0, 0) STG_B(4, 0, 0)
  VMCNT(0);
  BAR();

  for (int j2 = 0; j2 < NT2; j2 += 2) {
    GROUP(aK0b0, aK1b0, bK0b0, bK1b0, 1, j2 + 1, true)
    GROUP(aK0b1, aK1b1, bK0b1, bK1b1, 0, j2 + 2, (j2 + 2 < NT2))
  }
#undef GROUP
#undef RD_A
#undef RD_B
#undef MFMA20
#undef STG_A
#undef STG_B

  // ---- fused gate epilogue (r2-verified mapping) ----
  const int hc = h0 + wn * 16 + frow;
  const float b_f = bg[hc];
  const float b_i = bg[Hsz + hc];
  const float b_T = bg[2 * Hsz + hc];
  const float b_z = bg[3 * Hsz + hc];
  const float b_o = bg[4 * Hsz + hc];
  #pragma unroll
  for (int mi = 0; mi < 8; ++mi) {
    #pragma unroll
    for (int rr = 0; rr < 4; ++rr) {
      const int row = bm0 + wm * 128 + mi * 16 + kq * 4 + rr;
      const float fg = sigm(acc[mi][0][rr] + b_f);
      const float ig = sigm(acc[mi][1][rr] + b_i);
      const float Tg = sigm(acc[mi][2][rr] + b_T);
      const float zg = tanh_(acc[mi][3][rr] + b_z);
      const float og = sigm(acc[mi][4][rr] + b_o);
      const float cp = c_prev[(size_t)row * Hsz + hc];
      const float st = bf2f(A[(size_t)row * KG + 1024 + hc]);
      const float c = fg * cp + ig * zg + Tg * st;
      const float h = og * tanh_(c);
      out[(size_t)row * Hsz + hc] = h;
      out[(size_t)Bsz * Hsz + (size_t)row * Hsz + hc] = c;
    }
  }
}

extern "C" void kernel_launch(void* const* d_in, const int* in_sizes, int n_in,
                              void* d_out, int out_size, void* d_ws, size_t ws_size,
                              hipStream_t stream) {
  const float* x_t    = (const float*)d_in[0];
  const float* delta  = (const float*)d_in[1];
  const float* h_prev = (const float*)d_in[2];
  const float* c_prev = (const float*)d_in[3];
  const float* Ws     = (const float*)d_in[4];
  const float* bs     = (const float*)d_in[5];
  const float* Wg     = (const float*)d_in[6];
  const float* bg     = (const float*)d_in[7];
  float* out = (float*)d_out;

  char* wsb = (char*)d_ws;
  u16* A   = (u16*)(wsb);                          // [16384][1536] bf16
  u16* Wst = (u16*)(wsb + (size_t)50331648);       // [512][1024]  bf16
  u16* Wgt = (u16*)(wsb + (size_t)51380224);       // [2560][1536] bf16

  prep_A_kernel<<<dim3(16384), dim3(256), 0, stream>>>(h_prev, x_t, A);
  transpose_cast_kernel<<<dim3(16, 32), dim3(32, 8), 0, stream>>>(Ws, Wst, 1024, 512);
  transpose_cast_kernel<<<dim3(80, 48), dim3(32, 8), 0, stream>>>(Wg, Wgt, 1536, 2560);
  gemm1_kernel<<<dim3(4, 128), dim3(256), 0, stream>>>(A, Wst, Ws, bs, delta, A);
  gemm2_f<<<dim3(512), dim3(512), 0, stream>>>(A, Wgt, bg, c_prev, out);
}